// Round 3
// baseline (2715.778 us; speedup 1.0000x reference)
//
#include <hip/hip_runtime.h>
#include <math.h>

// Problem constants
#define B 64
#define S 2048
#define H 512
#define ENC 1024
#define EMB 128
#define V 50000
#define KX 1152   // EMB+ENC
#define KOUT 1664 // H+ENC+EMB

// ---- workspace offsets (floats) ----
#define XT_OFF      ((size_t)0)        // 1152*64
#define H00T_OFF    ((size_t)73728)    // 512*64
#define H01T_OFF    ((size_t)106496)   // 512*64
#define EMB_OFF     ((size_t)139264)   // 64*128 row-major
#define H0NT_OFF    ((size_t)147456)   // 512*64
#define ST_OFF      ((size_t)180224)   // 512*64
#define DEC_OFF     ((size_t)212992)   // 64*512 row-major
#define SCORES_OFF  ((size_t)245760)   // 64*2048
#define WPH_OFF     ((size_t)376832)   // 524288 ushorts (262144 floats): Wh^T bf16-hi packed [kb][n][8]
#define WPL_OFF     ((size_t)638976)   // 524288 ushorts: bf16-lo
#define OUTINT_OFF  ((size_t)901120)   // 1664*64
#define LOGITS_OFF  ((size_t)1007616)  // 64*50000
#define CPART_OFF   ((size_t)4207616)  // 64*8*1024
// total ws: ~18.9 MB

// ---- d_out offsets (floats) ----
#define FINAL_OFF   ((size_t)0)
#define HN_OFF      ((size_t)3200000)
#define CN_OFF      ((size_t)3265536)
#define CTX_OFF     ((size_t)3331072)
#define ATTN_OFF    ((size_t)3396608)
#define PGEN_OFF    ((size_t)3527680)
#define COVN_OFF    ((size_t)3527744)

typedef __attribute__((ext_vector_type(8)))  __bf16 bf16x8;
typedef __attribute__((ext_vector_type(8)))  short  short8v;
typedef __attribute__((ext_vector_type(16))) float  f32x16;
union BF8 { short8v s; bf16x8 b; };

__device__ __forceinline__ float sigf(float x){ return 1.0f/(1.0f+expf(-x)); }
__device__ __forceinline__ float tanhf_fast(float x){
  float e = __expf(2.0f*x);
  return 1.0f - 2.0f/(e + 1.0f);
}
__device__ __forceinline__ unsigned short f2bf(float x){
  unsigned int u = __float_as_uint(x);
  u += 0x7FFFu + ((u>>16)&1u);
  return (unsigned short)(u>>16);
}
__device__ __forceinline__ float bf2f(unsigned short h){
  return __uint_as_float(((unsigned int)h)<<16);
}

// K1: xT=[emb;context]^T, transpose h0[0]/h0[1], emb row-major,
//     pack att_Wh^T into bf16 hi/lo fragment layout [kb][n][8]
__global__ void k1_prep(const int* __restrict__ tok, const float* __restrict__ h0,
                        const float* __restrict__ cvec, const float* __restrict__ emb_w,
                        const float* __restrict__ att_Wh, float* __restrict__ ws){
  int i = blockIdx.x*256 + threadIdx.x;
  if (i < 73728){                                   // xT: k-major, b fastest
    int k = i>>6, b = i&63;
    ws[XT_OFF+i] = (k < EMB) ? emb_w[(size_t)tok[b]*EMB + k]
                             : cvec[(size_t)b*ENC + (k-EMB)];
  } else if (i < 106496){                           // h0[0]^T
    int j = i-73728; int k=j>>6, b=j&63;
    ws[H00T_OFF+j] = h0[(size_t)b*H + k];
  } else if (i < 139264){                           // h0[1]^T
    int j = i-106496; int k=j>>6, b=j&63;
    ws[H01T_OFF+j] = h0[(size_t)B*H + (size_t)b*H + k];
  } else if (i < 147456){                           // emb row-major
    int j = i-139264; int b=j>>7, k=j&127;
    ws[EMB_OFF+j] = emb_w[(size_t)tok[b]*EMB + k];
  } else {                                          // Wh^T packed bf16 hi/lo
    int j = i-147456;                               // j = kb*4096 + n*8 + e
    int e = j & 7, n = (j>>3) & 511, kb = j >> 12;
    float x = att_Wh[(size_t)n*ENC + kb*8 + e];
    unsigned short h  = f2bf(x);
    unsigned short lo = f2bf(x - bf2f(h));
    ((unsigned short*)(ws + WPH_OFF))[j] = h;
    ((unsigned short*)(ws + WPL_OFF))[j] = lo;
  }
}

// LSTM cell: 64 b-lanes x 4 h per block; wave-uniform weight rows -> scalar loads
template<int KA, int KB>
__global__ __launch_bounds__(256) void k_lstm(
    const float* __restrict__ xTa, const float* __restrict__ Wih,
    const float* __restrict__ xTb, const float* __restrict__ Whh,
    const float* __restrict__ bih, const float* __restrict__ bhh,
    const float* __restrict__ cprev, float* __restrict__ h_out,
    float* __restrict__ c_out, float* __restrict__ hT_out){
  int tid = threadIdx.x; int b = tid&63;
  int h = __builtin_amdgcn_readfirstlane(blockIdx.x*4 + (tid>>6));
  float a0=0.f,a1=0.f,a2=0.f,a3=0.f;
  const float* W0 = Wih + (size_t)h*KA;
  const float* W1 = Wih + (size_t)(h+H)*KA;
  const float* W2 = Wih + (size_t)(h+2*H)*KA;
  const float* W3 = Wih + (size_t)(h+3*H)*KA;
  #pragma unroll 4
  for (int k=0;k<KA;++k){
    float xv = xTa[k*64+b];
    a0 = fmaf(W0[k],xv,a0); a1 = fmaf(W1[k],xv,a1);
    a2 = fmaf(W2[k],xv,a2); a3 = fmaf(W3[k],xv,a3);
  }
  const float* U0 = Whh + (size_t)h*KB;
  const float* U1 = Whh + (size_t)(h+H)*KB;
  const float* U2 = Whh + (size_t)(h+2*H)*KB;
  const float* U3 = Whh + (size_t)(h+3*H)*KB;
  #pragma unroll 4
  for (int k=0;k<KB;++k){
    float hv = xTb[k*64+b];
    a0 = fmaf(U0[k],hv,a0); a1 = fmaf(U1[k],hv,a1);
    a2 = fmaf(U2[k],hv,a2); a3 = fmaf(U3[k],hv,a3);
  }
  a0 += bih[h]     + bhh[h];
  a1 += bih[h+H]   + bhh[h+H];
  a2 += bih[h+2*H] + bhh[h+2*H];
  a3 += bih[h+3*H] + bhh[h+3*H];
  float ig = sigf(a0), fg = sigf(a1), gg = tanhf(a2), og = sigf(a3);
  float c2 = fg*cprev[(size_t)b*H+h] + ig*gg;
  float h2 = og*tanhf(c2);
  h_out[(size_t)b*H+h] = h2;
  c_out[(size_t)b*H+h] = c2;
  hT_out[h*64+b] = h2;
}

// dec_feat[b][n] = sum_k att_Wd[n][k] * s[b][k]
__global__ __launch_bounds__(256) void k_decfeat(const float* __restrict__ sT,
    const float* __restrict__ Wd, float* __restrict__ dec){
  int tid=threadIdx.x, b=tid&63;
  int n=__builtin_amdgcn_readfirstlane(blockIdx.x*4 + (tid>>6));
  const float* Wr = Wd + (size_t)n*H;
  float a=0.f;
  #pragma unroll 4
  for (int k=0;k<H;++k) a = fmaf(Wr[k], sT[k*64+b], a);
  dec[(size_t)b*H+n]=a;
}

// Hot kernel: split-bf16 MFMA GEMM (64 rows x 512 cols per block, K=1024)
// + fused tanh/v epilogue. Wave w owns cols [128w,128w+128).
// v_mfma_f32_32x32x16_bf16 layouts:
//   A: row=l&31, k=(l>>5)*8+e ; B: k=(l>>5)*8+e, col=l&31
//   C/D: col=l&31, row=(r&3)+8*(r>>2)+4*(l>>5)
__global__ __launch_bounds__(256,2) void k_scores(
    const float* __restrict__ enc, const unsigned short* __restrict__ Wph,
    const unsigned short* __restrict__ Wpl, const float* __restrict__ dec,
    const float* __restrict__ cover, const float* __restrict__ Wc,
    const float* __restrict__ vvec, float* __restrict__ scores){
  __shared__ unsigned short Ah[2][4160];   // [kb(8) x 520] per buf, 520 = 64rows*8 + 8 pad
  __shared__ unsigned short Al[2][4160];
  __shared__ float red[4][64];
  int tid = threadIdx.x;
  int b  = blockIdx.x >> 5;
  int s0 = (blockIdx.x & 31) << 6;
  int w = tid>>6, l = tid&63, llo = l&31, lhi = l>>5;

  f32x16 acc[2][4];
  #pragma unroll
  for (int m=0;m<2;++m)
    #pragma unroll
    for (int nf=0;nf<4;++nf)
      #pragma unroll
      for (int c=0;c<16;++c) acc[m][nf][c] = 0.f;

  // staging: thread handles rows (tid>>4)+16i, cols (tid&15)*4..+3 of the 64x64 fp32 tile
  int srow = tid>>4, sf4 = tid&15;
  const float* gptr = enc + ((size_t)b*S + s0 + srow)*ENC + sf4*4;
  int wbase = (sf4>>1)*520 + srow*8 + (sf4&1)*4;  // ushort index; +128 per i
  float4 stg[4];

  #define LOADC(t) { _Pragma("unroll") \
    for (int i=0;i<4;++i) stg[i] = *(const float4*)(gptr + (size_t)(16*i)*ENC + (t)*64); }
  #define STOREC(buf) { _Pragma("unroll") \
    for (int i=0;i<4;++i){ \
      float xs0=stg[i].x, xs1=stg[i].y, xs2=stg[i].z, xs3=stg[i].w; \
      unsigned short h0=f2bf(xs0),h1=f2bf(xs1),h2=f2bf(xs2),h3=f2bf(xs3); \
      unsigned short l0=f2bf(xs0-bf2f(h0)),l1=f2bf(xs1-bf2f(h1)), \
                     l2=f2bf(xs2-bf2f(h2)),l3=f2bf(xs3-bf2f(h3)); \
      uint2 uh, ul; \
      uh.x = (unsigned)h0 | ((unsigned)h1<<16); uh.y = (unsigned)h2 | ((unsigned)h3<<16); \
      ul.x = (unsigned)l0 | ((unsigned)l1<<16); ul.y = (unsigned)l2 | ((unsigned)l3<<16); \
      *(uint2*)&Ah[buf][wbase + 128*i] = uh; \
      *(uint2*)&Al[buf][wbase + 128*i] = ul; \
    } }

  LOADC(0); STOREC(0);
  int cur = 0;
  const unsigned short* BhB = Wph + (size_t)lhi*4096 + (size_t)(w*128 + llo)*8;
  const unsigned short* BlB = Wpl + (size_t)lhi*4096 + (size_t)(w*128 + llo)*8;
  int aBase = lhi*520 + llo*8;

  for (int t=0;t<16;++t){
    __syncthreads();
    if (t<15) LOADC(t+1);
    #pragma unroll
    for (int kf=0;kf<4;++kf){
      BF8 ah0, ah1, al0, al1;
      ah0.s = *(const short8v*)&Ah[cur][aBase + kf*1040];
      ah1.s = *(const short8v*)&Ah[cur][aBase + kf*1040 + 256];
      al0.s = *(const short8v*)&Al[cur][aBase + kf*1040];
      al1.s = *(const short8v*)&Al[cur][aBase + kf*1040 + 256];
      size_t kOff = (size_t)(t*8 + kf*2)*4096;
      #pragma unroll
      for (int nf=0;nf<4;++nf){
        BF8 bh, bl;
        bh.s = *(const short8v*)(BhB + kOff + nf*256);
        bl.s = *(const short8v*)(BlB + kOff + nf*256);
        acc[0][nf] = __builtin_amdgcn_mfma_f32_32x32x16_bf16(ah0.b, bh.b, acc[0][nf], 0,0,0);
        acc[0][nf] = __builtin_amdgcn_mfma_f32_32x32x16_bf16(ah0.b, bl.b, acc[0][nf], 0,0,0);
        acc[0][nf] = __builtin_amdgcn_mfma_f32_32x32x16_bf16(al0.b, bh.b, acc[0][nf], 0,0,0);
        acc[1][nf] = __builtin_amdgcn_mfma_f32_32x32x16_bf16(ah1.b, bh.b, acc[1][nf], 0,0,0);
        acc[1][nf] = __builtin_amdgcn_mfma_f32_32x32x16_bf16(ah1.b, bl.b, acc[1][nf], 0,0,0);
        acc[1][nf] = __builtin_amdgcn_mfma_f32_32x32x16_bf16(al1.b, bh.b, acc[1][nf], 0,0,0);
      }
    }
    if (t<15) STOREC(cur^1);
    cur ^= 1;
  }

  // epilogue: scores[b][row] = sum_col v[col]*tanh(F + dec + cov*Wc)
  float dd[4], wcv[4], vvv[4];
  #pragma unroll
  for (int nf=0;nf<4;++nf){
    int col = w*128 + nf*32 + llo;
    dd[nf]  = dec[(size_t)b*H + col];
    wcv[nf] = Wc[col];
    vvv[nf] = vvec[col];
  }
  #pragma unroll
  for (int m=0;m<2;++m){
    #pragma unroll
    for (int r=0;r<16;++r){
      int row = m*32 + (r&3) + 8*(r>>2) + 4*lhi;
      float cov = cover[(size_t)b*S + s0 + row];
      float p = 0.f;
      #pragma unroll
      for (int nf=0;nf<4;++nf){
        float x = acc[m][nf][r] + dd[nf] + cov*wcv[nf];
        p = fmaf(vvv[nf], tanhf_fast(x), p);
      }
      #pragma unroll
      for (int off=16;off;off>>=1) p += __shfl_xor(p, off, 64);
      if (llo==0) red[w][row] = p;
    }
  }
  __syncthreads();
  if (tid < 64)
    scores[(size_t)b*S + s0 + tid] = red[0][tid]+red[1][tid]+red[2][tid]+red[3][tid];
}

// softmax over S per row + coverage update
__global__ __launch_bounds__(256) void k_attsoftmax(const float* __restrict__ scores,
     const int* __restrict__ mask, const float* __restrict__ cover,
     float* __restrict__ attn, float* __restrict__ covnew){
  __shared__ float shm[4];
  int b = blockIdx.x, t = threadIdx.x;
  float vals[8]; float mx = -3.0e38f;
  #pragma unroll
  for (int i=0;i<8;++i){
    int s = t + 256*i;
    float sc = scores[(size_t)b*S+s];
    if (mask[(size_t)b*S+s] == 0) sc = -10000.0f;
    vals[i] = sc; mx = fmaxf(mx, sc);
  }
  #pragma unroll
  for (int off=32;off;off>>=1) mx = fmaxf(mx, __shfl_xor(mx, off, 64));
  if ((t&63)==0) shm[t>>6] = mx;
  __syncthreads();
  mx = fmaxf(fmaxf(shm[0],shm[1]), fmaxf(shm[2],shm[3]));
  float sum = 0.f;
  #pragma unroll
  for (int i=0;i<8;++i){ vals[i] = expf(vals[i]-mx); sum += vals[i]; }
  #pragma unroll
  for (int off=32;off;off>>=1) sum += __shfl_xor(sum, off, 64);
  __syncthreads();
  if ((t&63)==0) shm[t>>6] = sum;
  __syncthreads();
  sum = (shm[0]+shm[1])+(shm[2]+shm[3]);
  float inv = 1.0f/sum;
  #pragma unroll
  for (int i=0;i<8;++i){
    int s = t + 256*i;
    float a = vals[i]*inv;
    attn[(size_t)b*S+s] = a;
    covnew[(size_t)b*S+s] = cover[(size_t)b*S+s] + a;
  }
}

// context = attn @ enc, two-phase deterministic reduction (phase 1)
__global__ __launch_bounds__(256) void k_ctx_partial(const float* __restrict__ attn,
    const float* __restrict__ enc, float* __restrict__ part){
  int blk = blockIdx.x;                       // 64 b * 4 ec * 8 sc
  int b = blk>>5, rest = blk&31, ec = rest>>3, sc = rest&7;
  int e = ec*256 + threadIdx.x;
  const float* attb = attn + (size_t)b*S;
  float acc = 0.f;
  int sb = sc*256;
  #pragma unroll 8
  for (int s=sb;s<sb+256;++s)
    acc = fmaf(attb[s], enc[((size_t)b*S + s)*ENC + e], acc);
  part[((size_t)b*8 + sc)*ENC + e] = acc;
}

// fused: phase-2 ctx reduction + out_inT assembly. out_inT[k][b] = [s; context; emb]
__global__ void k_ctxout(const float* __restrict__ part, const float* __restrict__ hN,
                         const float* __restrict__ emb, float* __restrict__ ctx,
                         float* __restrict__ xT){
  int idx = blockIdx.x*256 + threadIdx.x;     // 1664*64
  int k = idx>>6, b = idx&63;
  float v;
  if (k < H){
    v = hN[(size_t)B*H + (size_t)b*H + k];                         // h1n
  } else if (k < H+ENC){
    int e = k - H;
    float a = 0.f;
    #pragma unroll
    for (int sc=0;sc<8;++sc) a += part[((size_t)b*8+sc)*ENC + e];
    ctx[(size_t)b*ENC + e] = a;
    v = a;
  } else {
    v = emb[(size_t)b*EMB + (k-H-ENC)];
  }
  xT[idx] = v;
}

__global__ void k_pgen(const float* __restrict__ xT, const float* __restrict__ pgW,
                       const float* __restrict__ pgb, float* __restrict__ pgen){
  int b = blockIdx.x, l = threadIdx.x;        // 64 blocks x 1 wave
  float a = 0.f;
  for (int k=l;k<KOUT;k+=64) a = fmaf(pgW[k], xT[(size_t)k*64 + b], a);
  #pragma unroll
  for (int off=32;off;off>>=1) a += __shfl_xor(a, off, 64);
  if (l==0) pgen[b] = 1.0f/(1.0f+expf(-(a + pgb[0])));
}

// vocab logits: 64 rows/block, xT chunk staged in LDS (reused by all rows),
// W rows via wave-uniform scalar loads (read exactly once), LDS-transposed
// coalesced row-major writes.
#define VKC 128
__global__ __launch_bounds__(256,2) void k_vocab(const float* __restrict__ xT,
    const float* __restrict__ W, const float* __restrict__ bias, float* __restrict__ logits){
  __shared__ float xs[VKC][64];
  __shared__ float tbuf[4][16][65];
  int tid = threadIdx.x; int lane = tid&63;
  int w = __builtin_amdgcn_readfirstlane(tid>>6);
  int j0 = blockIdx.x*64 + w*16;
  const float* Wr[16];
  #pragma unroll
  for (int r=0;r<16;++r){
    int j = j0 + r; if (j >= V) j = V-1;
    Wr[r] = W + (size_t)j*KOUT;
  }
  float acc[16];
  #pragma unroll
  for (int r=0;r<16;++r) acc[r] = 0.f;

  for (int kc=0; kc<KOUT; kc+=VKC){
    __syncthreads();
    float4 sreg[8];
    #pragma unroll
    for (int i=0;i<8;++i){
      int idx = tid + 256*i; int kk = idx>>4, b4 = idx&15;
      sreg[i] = *(const float4*)(xT + (size_t)(kc+kk)*64 + b4*4);
    }
    #pragma unroll
    for (int i=0;i<8;++i){
      int idx = tid + 256*i; int kk = idx>>4, b4 = idx&15;
      *(float4*)&xs[kk][b4*4] = sreg[i];
    }
    __syncthreads();
    #pragma unroll 4
    for (int k=0;k<VKC;++k){
      float lv = xs[k][lane];
      #pragma unroll
      for (int r=0;r<16;++r) acc[r] = fmaf(Wr[r][kc+k], lv, acc[r]);
    }
  }
  // wave-local transpose -> coalesced row-major writes
  #pragma unroll
  for (int r=0;r<16;++r) tbuf[w][r][lane] = acc[r];
  int jj = lane&15;
  int j = j0 + jj;
  float bj = (j < V) ? bias[j] : 0.f;
  #pragma unroll
  for (int i=0;i<16;++i){
    int bb = (lane>>4) + 4*i;
    float val = tbuf[w][jj][bb] + bj;
    if (j < V) logits[(size_t)bb*V + j] = val;
  }
}

// vocab softmax * p_gen -> final
__global__ __launch_bounds__(1024) void k_vsoftmax(const float* __restrict__ logits,
    const float* __restrict__ pgen, float* __restrict__ fin){
  __shared__ float shm[16];
  int b = blockIdx.x, t = threadIdx.x;
  const float* row = logits + (size_t)b*V;
  float mx = -3.0e38f;
  for (int j=t;j<V;j+=1024) mx = fmaxf(mx, row[j]);
  #pragma unroll
  for (int off=32;off;off>>=1) mx = fmaxf(mx, __shfl_xor(mx, off, 64));
  if ((t&63)==0) shm[t>>6] = mx;
  __syncthreads();
  float m2 = shm[0];
  #pragma unroll
  for (int i=1;i<16;++i) m2 = fmaxf(m2, shm[i]);
  float sum = 0.f;
  for (int j=t;j<V;j+=1024) sum += expf(row[j]-m2);
  #pragma unroll
  for (int off=32;off;off>>=1) sum += __shfl_xor(sum, off, 64);
  __syncthreads();
  if ((t&63)==0) shm[t>>6] = sum;
  __syncthreads();
  float s2 = 0.f;
  #pragma unroll
  for (int i=0;i<16;++i) s2 += shm[i];
  float scale = pgen[b]/s2;
  float* frow = fin + (size_t)b*V;
  for (int j=t;j<V;j+=1024) frow[j] = scale*expf(row[j]-m2);
}

// pointer-generator scatter-add
__global__ void k_scatter(const float* __restrict__ attn, const float* __restrict__ pgen,
                          const int* __restrict__ ids, float* __restrict__ fin){
  int idx = blockIdx.x*256 + threadIdx.x;     // B*S
  int b = idx>>11;
  float cp = (1.0f - pgen[b]) * attn[idx];
  atomicAdd(&fin[(size_t)b*V + ids[idx]], cp);
}

extern "C" void kernel_launch(void* const* d_in, const int* in_sizes, int n_in,
                              void* d_out, int out_size, void* d_ws, size_t ws_size,
                              hipStream_t stream){
  const int*   tok    = (const int*)  d_in[0];
  const float* h0     = (const float*)d_in[1];
  const float* c0     = (const float*)d_in[2];
  const float* enc    = (const float*)d_in[3];
  const int*   mask   = (const int*)  d_in[4];
  const float* cvec   = (const float*)d_in[5];
  const float* cover  = (const float*)d_in[6];
  const int*   eids   = (const int*)  d_in[7];
  const float* emb_w  = (const float*)d_in[8];
  const float* Wih0   = (const float*)d_in[9];
  const float* Whh0   = (const float*)d_in[10];
  const float* bih0   = (const float*)d_in[11];
  const float* bhh0   = (const float*)d_in[12];
  const float* Wih1   = (const float*)d_in[13];
  const float* Whh1   = (const float*)d_in[14];
  const float* bih1   = (const float*)d_in[15];
  const float* bhh1   = (const float*)d_in[16];
  const float* att_Wh = (const float*)d_in[17];
  const float* att_Wd = (const float*)d_in[18];
  const float* att_Wc = (const float*)d_in[19];
  const float* att_v  = (const float*)d_in[20];
  const float* out_W  = (const float*)d_in[21];
  const float* out_b  = (const float*)d_in[22];
  const float* pg_W   = (const float*)d_in[23];
  const float* pg_b   = (const float*)d_in[24];
  float* out = (float*)d_out;
  float* ws  = (float*)d_ws;

  k1_prep<<<2624, 256, 0, stream>>>(tok, h0, cvec, emb_w, att_Wh, ws);

  k_lstm<KX,H><<<128, 256, 0, stream>>>(ws+XT_OFF, Wih0, ws+H00T_OFF, Whh0,
      bih0, bhh0, c0, out+HN_OFF, out+CN_OFF, ws+H0NT_OFF);

  k_lstm<H,H><<<128, 256, 0, stream>>>(ws+H0NT_OFF, Wih1, ws+H01T_OFF, Whh1,
      bih1, bhh1, c0+(size_t)B*H, out+HN_OFF+(size_t)B*H, out+CN_OFF+(size_t)B*H, ws+ST_OFF);

  k_decfeat<<<128, 256, 0, stream>>>(ws+ST_OFF, att_Wd, ws+DEC_OFF);

  k_scores<<<2048, 256, 0, stream>>>(enc,
      (const unsigned short*)(ws + WPH_OFF), (const unsigned short*)(ws + WPL_OFF),
      ws+DEC_OFF, cover, att_Wc, att_v, ws+SCORES_OFF);

  k_attsoftmax<<<64, 256, 0, stream>>>(ws+SCORES_OFF, mask, cover,
      out+ATTN_OFF, out+COVN_OFF);

  k_ctx_partial<<<2048, 256, 0, stream>>>(out+ATTN_OFF, enc, ws+CPART_OFF);

  k_ctxout<<<416, 256, 0, stream>>>(ws+CPART_OFF, out+HN_OFF, ws+EMB_OFF,
      out+CTX_OFF, ws+OUTINT_OFF);

  k_pgen<<<64, 64, 0, stream>>>(ws+OUTINT_OFF, pg_W, pg_b, out+PGEN_OFF);

  k_vocab<<<782, 256, 0, stream>>>(ws+OUTINT_OFF, out_W, out_b, ws+LOGITS_OFF);
  k_vsoftmax<<<64, 1024, 0, stream>>>(ws+LOGITS_OFF, out+PGEN_OFF, out+FINAL_OFF);
  k_scatter<<<512, 256, 0, stream>>>(out+ATTN_OFF, out+PGEN_OFF, eids, out+FINAL_OFF);
}